// Round 16
// baseline (71.116 us; speedup 1.0000x reference)
//
#include <hip/hip_runtime.h>
#include <stdint.h>

#define BATCH 2048
#define INF 1024
#define OUTF 1024
#define GRID_G 8
#define KTOT 9216   // INF + INF*GRID_G

#define SK 8
#define KC (KTOT / SK)   // 1152
#define BK 64
#define NKT (KC / BK)    // 18
#define MTT 8            // BATCH/256
#define NTT 4            // OUTF/256
#define CSLAB ((size_t)BATCH * OUTF)

#define WBLK (OUTF * (KTOT / 8) / 256)   // 4608 Wcat blocks
#define ABLK (BATCH * INF / 256)         // 8192 Acat blocks

typedef __attribute__((ext_vector_type(8))) short short8_t;
typedef __attribute__((ext_vector_type(4))) float f32x4_t;
typedef __attribute__((ext_vector_type(8))) unsigned short u16x8_t;

__device__ __forceinline__ unsigned short f2bf(float f) {
  unsigned int u = __float_as_uint(f);
  u += 0x7FFFu + ((u >> 16) & 1u);
  return (unsigned short)(u >> 16);
}

__device__ __forceinline__ float bf2f(unsigned short h) {
  return __uint_as_float((unsigned int)h << 16);
}

__device__ __forceinline__ void async16(void* lds, const void* g) {
  __builtin_amdgcn_global_load_lds(
      (const __attribute__((address_space(1))) void*)g,
      (__attribute__((address_space(3))) void*)lds, 16, 0, 0);
}

// Merged prep: blocks [0,WBLK) build Wcat (8 elem/thread); blocks
// [WBLK, WBLK+ABLK) build dense Acat (one (b,i) per thread: x bf16 + one-hot).
__global__ __launch_bounds__(256) void build_all_kernel(
    const float* __restrict__ bw, const float* __restrict__ coeff,
    const float* __restrict__ x, const float* __restrict__ grid,
    unsigned short* __restrict__ wc, unsigned short* __restrict__ ac) {
  int blk = blockIdx.x;
  if (blk < WBLK) {
    int id = blk * 256 + threadIdx.x;
    int row = id / (KTOT / 8);
    int k8 = id - row * (KTOT / 8);
    int k = k8 * 8;
    const float* src = (k < INF) ? (bw + (size_t)row * INF + k)
                                 : (coeff + (size_t)row * (INF * GRID_G) + (k - INF));
    const float4* s4 = (const float4*)src;
    float4 a = s4[0], b = s4[1];
    u16x8_t v;
    v[0] = f2bf(a.x); v[1] = f2bf(a.y); v[2] = f2bf(a.z); v[3] = f2bf(a.w);
    v[4] = f2bf(b.x); v[5] = f2bf(b.y); v[6] = f2bf(b.z); v[7] = f2bf(b.w);
    *(u16x8_t*)(wc + (size_t)id * 8) = v;
  } else {
    __shared__ float sg[GRID_G + 1];
    if (threadIdx.x <= GRID_G) sg[threadIdx.x] = grid[threadIdx.x];
    __syncthreads();
    int id = (blk - WBLK) * 256 + threadIdx.x;  // one per (b,i)
    int b = id >> 10;
    int i = id & 1023;
    float xv = x[id];
    ac[(size_t)b * KTOT + i] = f2bf(xv);
    float xc = fminf(fmaxf(xv, -1.0f), 1.0f);
    int cnt = 0;
#pragma unroll
    for (int j = 0; j <= GRID_G; ++j) cnt += (xc >= sg[j]) ? 1 : 0;
    int idx = cnt - 1;
    idx = idx < 0 ? 0 : (idx > GRID_G - 1 ? GRID_G - 1 : idx);
    float left = sg[idx], right = sg[idx + 1];
    float denom = right - left;
    denom = (denom == 0.0f) ? 1.0f : denom;
    float w = (xc - left) / denom;
    unsigned short val = f2bf(0.1f * w);
    u16x8_t v;
#pragma unroll
    for (int g = 0; g < GRID_G; ++g) v[g] = (g == idx) ? val : (unsigned short)0;
    *(u16x8_t*)(ac + (size_t)b * KTOT + INF + (size_t)i * 8) = v;
  }
}

// 256x256xBK64 split-K GEMM with 128x128 WAVE TILES (4 waves, 2x2 grid).
// Rationale: LDS is per-CU-shared, MFMA per-SIMD. Per wave per K64-tile:
// reads R = 16+16 = 32 b128, MFMA M = 128 -> cap = (M/4waves.. ) 40% vs the
// 27% cap of all previous 128x64-wave variants (R5-R15 measured 23-26%).
// 1 wave/SIMD (256 acc VGPR) by design. Counted gates: every phase stages
// 8 async16/wave; gate = vmcnt(8) (the 8 newest stay in flight), final
// phase vmcnt(0). Barrier-ordered WAR on regions (read one tile before
// rewrite, two barriers apart). Chunk-transposed 1KB units: conflict-free.
__global__ __launch_bounds__(256, 1) void gemm_kernel(
    const unsigned short* __restrict__ A, const unsigned short* __restrict__ W,
    unsigned short* __restrict__ P) {
  __shared__ unsigned short LA[2][2][256 * 32];  // 64 KB
  __shared__ unsigned short LB[2][2][256 * 32];  // 64 KB

  int bid = blockIdx.x;
  int sk = bid & 7;          // XCD<->sk-slab affinity (7 MB working set per L2)
  int t0 = bid >> 3;         // 0..31
  int mt = t0 >> 2, nt = t0 & 3;

  int tid = threadIdx.x, wave = tid >> 6, lane = tid & 63;
  int wr = wave >> 1, wc = wave & 1;   // 2x2 wave grid; 128x128 C per wave
  int lr = lane & 15, lk = lane >> 4;
  int rlo = lk * 128 + lr * 8;         // chunk-transposed intra-unit offset

  // staging (chunk-transpose): each wave stages 4 units/region (64 rows);
  // lane l -> row wave*64 + j*16 + (l&15), chunk l>>4
  int scol = (lane >> 4) * 8;
  const unsigned short* gA = A + (size_t)(mt * 256 + wave * 64 + (lane & 15)) * KTOT + sk * KC + scol;
  const unsigned short* gB = W + (size_t)(nt * 256 + wave * 64 + (lane & 15)) * KTOT + sk * KC + scol;
  const size_t r16 = (size_t)16 * KTOT;

  f32x4_t acc[8][8];
#pragma unroll
  for (int mf = 0; mf < 8; ++mf)
#pragma unroll
    for (int nf = 0; nf < 8; ++nf) acc[mf][nf] = f32x4_t{0.f, 0.f, 0.f, 0.f};

#define VMW(N) asm volatile("s_waitcnt vmcnt(" #N ")" ::: "memory")
#define BARR() { __builtin_amdgcn_s_barrier(); asm volatile("" ::: "memory"); }
#define STG(REGP, gptr, ko) { \
    unsigned short* d_ = (REGP) + wave * 2048; \
    async16(d_,        gptr + (ko)); \
    async16(d_ + 512,  gptr + r16 + (ko)); \
    async16(d_ + 1024, gptr + 2 * r16 + (ko)); \
    async16(d_ + 1536, gptr + 3 * r16 + (ko)); }

  // prologue: tile 0 -> buf 0, order A(k0) B(k0) A(k1) B(k1)
  STG(&LA[0][0][0], gA, 0) STG(&LB[0][0][0], gB, 0)
  STG(&LA[0][1][0], gA, 32) STG(&LB[0][1][0], gB, 32)

  for (int t = 0; t < NKT; ++t) {
    int c = t & 1, nb = c ^ 1;
    int ko = (t + 1) * BK;
    bool pf = (t + 1) < NKT;
#pragma unroll
    for (int ks = 0; ks < 2; ++ks) {
      bool last = (!pf) && (ks == 1);
      if (last) { VMW(0); } else { VMW(8); }
      BARR();
      short8_t af[8], bf[8];
#pragma unroll
      for (int mf = 0; mf < 8; ++mf)
        af[mf] = *(const short8_t*)&LA[c][ks][(wr * 8 + mf) * 512 + rlo];
#pragma unroll
      for (int nf = 0; nf < 8; ++nf)
        bf[nf] = *(const short8_t*)&LB[c][ks][(wc * 8 + nf) * 512 + rlo];
      if (pf) {
        STG(&LA[nb][ks][0], gA, ko + ks * 32)
        STG(&LB[nb][ks][0], gB, ko + ks * 32)
      }
      __builtin_amdgcn_s_setprio(1);
#pragma unroll
      for (int mf = 0; mf < 8; ++mf)
#pragma unroll
        for (int nf = 0; nf < 8; ++nf)
          acc[mf][nf] = __builtin_amdgcn_mfma_f32_16x16x32_bf16(
              af[mf], bf[nf], acc[mf][nf], 0, 0, 0);
      __builtin_amdgcn_s_setprio(0);
    }
  }

  // epilogue: C/D col=lane&15 (n), row=(lane>>4)*4+reg (m); private bf16 slab
  unsigned short* slab = P + (size_t)sk * CSLAB;
#pragma unroll
  for (int mf = 0; mf < 8; ++mf) {
#pragma unroll
    for (int nf = 0; nf < 8; ++nf) {
      int col = nt * 256 + wc * 128 + nf * 16 + lr;
      int rowb = mt * 256 + wr * 128 + mf * 16 + lk * 4;
#pragma unroll
      for (int r = 0; r < 4; ++r)
        slab[(size_t)(rowb + r) * OUTF + col] = f2bf(acc[mf][nf][r]);
    }
  }
}

// out[e] = sum over 8 partial slabs; 8 elements/thread, overwrites d_out.
__global__ __launch_bounds__(256) void reduce_kernel(
    const unsigned short* __restrict__ P, float* __restrict__ out) {
  size_t base = ((size_t)blockIdx.x * 256 + threadIdx.x) * 8;
  float s[8];
#pragma unroll
  for (int j = 0; j < 8; ++j) s[j] = 0.0f;
#pragma unroll
  for (int k = 0; k < SK; ++k) {
    u16x8_t v = *(const u16x8_t*)(P + (size_t)k * CSLAB + base);
#pragma unroll
    for (int j = 0; j < 8; ++j)
      s[j] += bf2f(v[j]);
  }
  float4 lo = {s[0], s[1], s[2], s[3]};
  float4 hi = {s[4], s[5], s[6], s[7]};
  *(float4*)(out + base) = lo;
  *(float4*)(out + base + 4) = hi;
}

extern "C" void kernel_launch(void* const* d_in, const int* in_sizes, int n_in,
                              void* d_out, int out_size, void* d_ws, size_t ws_size,
                              hipStream_t stream) {
  const float* x = (const float*)d_in[0];
  const float* bw = (const float*)d_in[1];
  const float* coeff = (const float*)d_in[2];
  const float* grid = (const float*)d_in[3];
  float* out = (float*)d_out;

  unsigned short* Acat = (unsigned short*)d_ws;              // 37.75 MB
  unsigned short* Wcat = Acat + (size_t)BATCH * KTOT;        // 18.87 MB
  unsigned short* Part = Wcat + (size_t)OUTF * KTOT;         // 33.55 MB

  build_all_kernel<<<WBLK + ABLK, 256, 0, stream>>>(bw, coeff, x, grid, Wcat, Acat);
  gemm_kernel<<<SK * MTT * NTT, 256, 0, stream>>>(Acat, Wcat, Part);
  reduce_kernel<<<(int)(CSLAB / 8 / 256), 256, 0, stream>>>(Part, out);
}

// Round 17
// 67.920 us; speedup vs baseline: 1.0471x; 1.0471x over previous
//
#include <hip/hip_runtime.h>
#include <stdint.h>

#define BATCH 2048
#define INF 1024
#define OUTF 1024
#define GRID_G 8
#define KTOT 9216   // INF + INF*GRID_G (Wcat layout)

#define SK 8
#define MTT 8            // BATCH/256
#define NTT 4            // OUTF/256
#define CSLAB ((size_t)BATCH * OUTF)

#define WITEMS (OUTF * (KTOT / 8))        // 1179648 build_w items (8 elem each)
#define WBLK (WITEMS / 256)               // 4608 blocks
#define ABLK ((BATCH * INF / 4) / 256)    // 2048 blocks (4 elem/thread)

typedef __attribute__((ext_vector_type(8))) short short8_t;
typedef __attribute__((ext_vector_type(4))) float f32x4_t;
typedef __attribute__((ext_vector_type(8))) unsigned short u16x8_t;

__device__ __forceinline__ unsigned short f2bf(float f) {
  unsigned int u = __float_as_uint(f);
  u += 0x7FFFu + ((u >> 16) & 1u);
  return (unsigned short)(u >> 16);
}

__device__ __forceinline__ float bf2f(unsigned short h) {
  return __uint_as_float((unsigned int)h << 16);
}

__device__ __forceinline__ void async16(void* lds, const void* g) {
  __builtin_amdgcn_global_load_lds(
      (const __attribute__((address_space(1))) void*)g,
      (__attribute__((address_space(3))) void*)lds, 16, 0, 0);
}

// frag[j] = (j==idx) ? w : 0 over 8 bf16, from packed (bf16 w | idx<<16)
__device__ __forceinline__ short8_t onehot_frag(unsigned int p) {
  unsigned int wlo = p & 0xFFFFu;
  unsigned int idx = p >> 16;
  unsigned int sel = (idx & 1u) ? (wlo << 16) : wlo;
  unsigned int jt = idx >> 1;
  union { unsigned int u[4]; short8_t s; } r;
  r.u[0] = (jt == 0u) ? sel : 0u;
  r.u[1] = (jt == 1u) ? sel : 0u;
  r.u[2] = (jt == 2u) ? sel : 0u;
  r.u[3] = (jt == 3u) ? sel : 0u;
  return r.s;
}

// Merged prep: blocks [0,WBLK) build Wcat (8 elem/thread); blocks [WBLK,
// WBLK+ABLK) build Xbf + Apack (4 elem/thread, float4-vectorized).
__global__ __launch_bounds__(256) void build_all_kernel(
    const float* __restrict__ bw, const float* __restrict__ coeff,
    const float* __restrict__ x, const float* __restrict__ grid,
    unsigned short* __restrict__ wc, unsigned short* __restrict__ xbf,
    unsigned int* __restrict__ ap) {
  int blk = blockIdx.x;
  if (blk < WBLK) {
    int id = blk * 256 + threadIdx.x;
    int row = id / (KTOT / 8);
    int k8 = id - row * (KTOT / 8);
    int k = k8 * 8;
    const float* src = (k < INF) ? (bw + (size_t)row * INF + k)
                                 : (coeff + (size_t)row * (INF * GRID_G) + (k - INF));
    const float4* s4 = (const float4*)src;
    float4 a = s4[0], b = s4[1];
    u16x8_t v;
    v[0] = f2bf(a.x); v[1] = f2bf(a.y); v[2] = f2bf(a.z); v[3] = f2bf(a.w);
    v[4] = f2bf(b.x); v[5] = f2bf(b.y); v[6] = f2bf(b.z); v[7] = f2bf(b.w);
    *(u16x8_t*)(wc + (size_t)id * 8) = v;
  } else {
    __shared__ float sg[GRID_G + 1];
    if (threadIdx.x <= GRID_G) sg[threadIdx.x] = grid[threadIdx.x];
    __syncthreads();
    int id4 = (blk - WBLK) * 256 + threadIdx.x;   // one per 4 elements
    float4 xv4 = *(const float4*)(x + (size_t)id4 * 4);
    float xs[4] = {xv4.x, xv4.y, xv4.z, xv4.w};
    unsigned short xb[4];
    unsigned int ph[4];
#pragma unroll
    for (int e = 0; e < 4; ++e) {
      float xv = xs[e];
      xb[e] = f2bf(xv);
      float xc = fminf(fmaxf(xv, -1.0f), 1.0f);
      int cnt = 0;
#pragma unroll
      for (int j = 0; j <= GRID_G; ++j) cnt += (xc >= sg[j]) ? 1 : 0;
      int idx = cnt - 1;
      idx = idx < 0 ? 0 : (idx > GRID_G - 1 ? GRID_G - 1 : idx);
      float left = sg[idx], right = sg[idx + 1];
      float denom = right - left;
      denom = (denom == 0.0f) ? 1.0f : denom;
      float w = (xc - left) / denom;
      ph[e] = (unsigned int)f2bf(0.1f * w) | ((unsigned int)idx << 16);
    }
    *(ushort2*)(xbf + (size_t)id4 * 4) = ushort2{xb[0], xb[1]};
    *(ushort2*)(xbf + (size_t)id4 * 4 + 2) = ushort2{xb[2], xb[3]};
    uint4 pv = {ph[0], ph[1], ph[2], ph[3]};
    *(uint4*)(ap + (size_t)id4 * 4) = pv;
  }
}

// Fused 256x256 split-K GEMM — best measured core (~880 TF in-graph).
// 2 dense base tiles (Xbf) + 16 spline tiles (packed-A, in-reg one-hot).
// sk = bid&7: XCD<->slab affinity (each XCD touches only its 7 MB slice).
__global__ __launch_bounds__(512, 2) void fused_gemm_kernel(
    const unsigned short* __restrict__ Xb, const unsigned int* __restrict__ Ap,
    const unsigned short* __restrict__ Wc, unsigned short* __restrict__ P) {
  __shared__ unsigned short LA[2][2][256 * 32];  // 64 KB
  __shared__ unsigned short LB[2][2][256 * 32];  // 64 KB

  int bid = blockIdx.x;
  int sk = bid & 7;          // XCD affinity
  int t0i = bid >> 3;        // 0..31
  int mt = t0i >> 2, nt = t0i & 3;

  int tid = threadIdx.x, wave = tid >> 6, lane = tid & 63;
  int wr = wave >> 2, wc = wave & 3;   // 2x4 wave grid; per-wave C = 128x64
  int lr = lane & 15, lk = lane >> 4;
  int rlo = lk * 128 + lr * 8;         // chunk-transposed read offset

  int srow = wave * 16 + (lane & 15);
  int scol = ((lane >> 4) & 3) * 8;
  const unsigned short* gXA  = Xb + (size_t)(mt * 256 + srow) * INF + sk * 128 + scol;
  const unsigned short* gXA2 = gXA + (size_t)128 * INF;
  const unsigned short* gB   = Wc + (size_t)(nt * 256 + srow) * KTOT + scol;
  const unsigned short* gB2  = gB + (size_t)128 * KTOT;
  const unsigned int* gAP = Ap + (size_t)(mt * 256 + wave * 32 + (lane >> 1)) * INF
                            + sk * 128 + (lane & 1) * 4;

  unsigned int* APK0 = (unsigned int*)&LA[0][0][0];
  unsigned int* APK1 = (unsigned int*)&LA[1][0][0];

  const int CB = sk * 128;           // base col range base
  const int CS = 1024 + sk * 1024;   // spline col range base

  f32x4_t acc[2][4][4];
#pragma unroll
  for (int ch = 0; ch < 2; ++ch)
#pragma unroll
    for (int mf = 0; mf < 4; ++mf)
#pragma unroll
      for (int nf = 0; nf < 4; ++nf) acc[ch][mf][nf] = f32x4_t{0.f, 0.f, 0.f, 0.f};

#define VMW(N) asm volatile("s_waitcnt vmcnt(" #N ")" ::: "memory")
#define BARR() { __builtin_amdgcn_s_barrier(); asm volatile("" ::: "memory"); }
#define STAGE_XA(nb, ks, colofs) { unsigned short* d_ = &LA[nb][ks][wave * 512]; \
    async16(d_, gXA + (colofs) + (ks) * 32); \
    async16(d_ + 4096, gXA2 + (colofs) + (ks) * 32); }
#define STAGE_B(nb, ks, colofs) { unsigned short* d_ = &LB[nb][ks][wave * 512]; \
    async16(d_, gB + (colofs) + (ks) * 32); \
    async16(d_ + 4096, gB2 + (colofs) + (ks) * 32); }
#define STAGE_APK(APKn, tt) { async16((void*)((APKn) + wave * 256), gAP + ((tt) - 2) * 8); }
#define DSR_A(af_, CC, ks, ch) { _Pragma("unroll") for (int mf = 0; mf < 4; ++mf) \
    af_[mf] = *(const short8_t*)&LA[CC][ks][(wr * 8 + (ch) * 4 + mf) * 512 + rlo]; }
#define DSR_B(bf_, CC, ks) { _Pragma("unroll") for (int nf = 0; nf < 4; ++nf) \
    bf_[nf] = *(const short8_t*)&LB[CC][ks][(wc * 4 + nf) * 512 + rlo]; }
#define PRD(pr_, APKc, ks, ch) { _Pragma("unroll") for (int mf = 0; mf < 4; ++mf) \
    pr_[mf] = (APKc)[(wr * 128 + (ch) * 64 + mf * 16 + lr) * 8 + (ks) * 4 + lk]; }
#define EXPAND(af_, pr_) { _Pragma("unroll") for (int mf = 0; mf < 4; ++mf) \
    af_[mf] = onehot_frag(pr_[mf]); }
#define MFMA16(CH, af_, bf_) { __builtin_amdgcn_s_setprio(1); \
    _Pragma("unroll") for (int mf = 0; mf < 4; ++mf) \
    _Pragma("unroll") for (int nf = 0; nf < 4; ++nf) \
      acc[CH][mf][nf] = __builtin_amdgcn_mfma_f32_16x16x32_bf16( \
          af_[mf], bf_[nf], acc[CH][mf][nf], 0, 0, 0); \
    __builtin_amdgcn_s_setprio(0); }

  // prologue: tile0 (base) into buf0; order A0,B0,A1,B1
  STAGE_XA(0, 0, 0) STAGE_B(0, 0, CB) STAGE_XA(0, 1, 0) STAGE_B(0, 1, CB)

  { // tile0: base, c=0; stages t1(base)->buf1
    short8_t af[4], bf[4];
    VMW(4); BARR();
    DSR_A(af, 0, 0, 0) DSR_B(bf, 0, 0)
    STAGE_XA(1, 0, 64)
    MFMA16(0, af, bf)
    DSR_A(af, 0, 0, 1)
    STAGE_B(1, 0, CB + 64)
    MFMA16(1, af, bf)
    VMW(4); BARR();
    DSR_A(af, 0, 1, 0) DSR_B(bf, 0, 1)
    STAGE_XA(1, 1, 64)
    MFMA16(0, af, bf)
    DSR_A(af, 0, 1, 1)
    STAGE_B(1, 1, CB + 64)
    MFMA16(1, af, bf)
  }
  { // tile1: base, c=1; stages t2(spline)->buf0: APK@ph0, B0@ph1, B1@ph2
    short8_t af[4], bf[4];
    VMW(4); BARR();
    DSR_A(af, 1, 0, 0) DSR_B(bf, 1, 0)
    STAGE_APK(APK0, 2)
    MFMA16(0, af, bf)
    DSR_A(af, 1, 0, 1)
    STAGE_B(0, 0, CS)
    MFMA16(1, af, bf)
    VMW(3); BARR();
    DSR_A(af, 1, 1, 0) DSR_B(bf, 1, 1)
    STAGE_B(0, 1, CS)
    MFMA16(0, af, bf)
    DSR_A(af, 1, 1, 1)
    MFMA16(1, af, bf)
  }
  // spline tiles t=2..17
  for (int t = 2; t < 18; ++t) {
    int c = t & 1;
    unsigned int* APKc = c ? APK1 : APK0;
    unsigned int* APKn = c ? APK0 : APK1;
    int nb = c ^ 1;
    bool pf = t < 17;
    int cs = CS + (t - 1) * 64;   // (t+1-2)*64
    short8_t af[4], bf[4];
    unsigned int pr[4];
    VMW(2); BARR();
    PRD(pr, APKc, 0, 0) DSR_B(bf, c, 0)
    if (pf) STAGE_APK(APKn, t + 1)
    EXPAND(af, pr) MFMA16(0, af, bf)
    PRD(pr, APKc, 0, 1)
    if (pf) STAGE_B(nb, 0, cs)
    EXPAND(af, pr) MFMA16(1, af, bf)
    if (pf) { VMW(3); } else { VMW(0); }
    BARR();
    PRD(pr, APKc, 1, 0) DSR_B(bf, c, 1)
    if (pf) STAGE_B(nb, 1, cs)
    EXPAND(af, pr) MFMA16(0, af, bf)
    PRD(pr, APKc, 1, 1)
    EXPAND(af, pr) MFMA16(1, af, bf)
  }

  // epilogue: C/D col=lane&15 (n), row=(lane>>4)*4+reg (m); private bf16 slab
  unsigned short* slab = P + (size_t)sk * CSLAB;
#pragma unroll
  for (int ch = 0; ch < 2; ++ch)
#pragma unroll
    for (int mf = 0; mf < 4; ++mf)
#pragma unroll
      for (int nf = 0; nf < 4; ++nf) {
        int col = nt * 256 + wc * 64 + nf * 16 + lr;
        int rowb = mt * 256 + wr * 128 + ch * 64 + mf * 16 + lk * 4;
#pragma unroll
        for (int r = 0; r < 4; ++r)
          slab[(size_t)(rowb + r) * OUTF + col] = f2bf(acc[ch][mf][nf][r]);
      }
}

// out[e] = sum over 8 partial slabs; 8 elements/thread, overwrites d_out.
__global__ __launch_bounds__(256) void reduce_kernel(
    const unsigned short* __restrict__ P, float* __restrict__ out) {
  size_t base = ((size_t)blockIdx.x * 256 + threadIdx.x) * 8;
  float s[8];
#pragma unroll
  for (int j = 0; j < 8; ++j) s[j] = 0.0f;
#pragma unroll
  for (int k = 0; k < SK; ++k) {
    u16x8_t v = *(const u16x8_t*)(P + (size_t)k * CSLAB + base);
#pragma unroll
    for (int j = 0; j < 8; ++j)
      s[j] += bf2f(v[j]);
  }
  float4 lo = {s[0], s[1], s[2], s[3]};
  float4 hi = {s[4], s[5], s[6], s[7]};
  *(float4*)(out + base) = lo;
  *(float4*)(out + base + 4) = hi;
}

extern "C" void kernel_launch(void* const* d_in, const int* in_sizes, int n_in,
                              void* d_out, int out_size, void* d_ws, size_t ws_size,
                              hipStream_t stream) {
  const float* x = (const float*)d_in[0];
  const float* bw = (const float*)d_in[1];
  const float* coeff = (const float*)d_in[2];
  const float* grid = (const float*)d_in[3];
  float* out = (float*)d_out;

  unsigned short* Wcat = (unsigned short*)d_ws;                        // 18.87 MB
  unsigned short* Xbf  = Wcat + (size_t)OUTF * KTOT;                   //  4.19 MB
  unsigned int*   Apack = (unsigned int*)(Xbf + (size_t)BATCH * INF);  //  8.39 MB
  unsigned short* Part = (unsigned short*)(Apack + (size_t)BATCH * INF); // 8 x 4.19 MB

  build_all_kernel<<<WBLK + ABLK, 256, 0, stream>>>(bw, coeff, x, grid, Wcat, Xbf, Apack);
  fused_gemm_kernel<<<SK * MTT * NTT, 512, 0, stream>>>(Xbf, Apack, Wcat, Part);
  reduce_kernel<<<(int)(CSLAB / 8 / 256), 256, 0, stream>>>(Part, out);
}